// Round 7
// baseline (147.323 us; speedup 1.0000x reference)
//
#include <hip/hip_runtime.h>
#include <math.h>

#define D 512
#define NC 64
#define NQ 2048

typedef unsigned short u16;
typedef __attribute__((ext_vector_type(8))) short bf8;
typedef __attribute__((ext_vector_type(4))) float f4;

// ---- workspace float offsets ----
#define OFF_S    0
#define OFF_L    32                      // 512x512 fp32 L; REUSED later as YYf (UWp fp32)
#define OFF_W    (OFF_L + D*D)           // 512x512 fp32 W
#define OFF_TMP  (OFF_W + D*D)           // 256x256 doubling temp
#define OFF_ABH  (OFF_TMP + 65536)       // 2560x512 u16 (rows 0-511 Ubp, 512+ Xq) hi
#define OFF_ABL  (OFF_ABH + 655360)      // lo
#define OFF_WH   (OFF_ABL + 655360)      // 512x512 u16 W hi
#define OFF_WL   (OFF_WH + 131072)
#define OFF_YYH  (OFF_WL + 131072)       // 2560x512 u16 YY hi (rows 0-511 UWp, 512+ Y)
#define OFF_YYL  (OFF_YYH + 655360)
#define OFF_AQ   (OFF_YYL + 655360)      // 2048 fp32
#define OFF_MINV (OFF_AQ + NQ)
#define OFF_BIAS (OFF_MINV + NC*36)
#define OFF_H    (OFF_BIAS + NC)
#define OFF_SV   (OFF_H + NC)            // NC*6
// total ~ 3.48M floats ~ 13.9 MB

__device__ inline float wred(float v) {
#pragma unroll
  for (int off = 32; off; off >>= 1) v += __shfl_down(v, off);
  return v;
}

// split fp32 into hi bf16 (truncated, so v-hi is exact) + lo bf16 (RN)
__device__ inline void split2(float v, u16& h, u16& l) {
  unsigned u = __float_as_uint(v);
  h = (u16)(u >> 16);
  float hf = __uint_as_float(u & 0xFFFF0000u);
  float r = v - hf;
  unsigned ru = __float_as_uint(r);
  l = (u16)((ru + 0x7FFFu + ((ru >> 16) & 1u)) >> 16);
}

// Fused prep: 0..1023 build L (+zero W upper, fp32+bf16), 1024..1087 classprep
// (write Ubp directly as bf16 hi/lo), 1088 scalars, 1089..1600 Xq->bf16 hi/lo.
__global__ __launch_bounds__(256) void k_prep(const float* __restrict__ diag,
                                              const float* __restrict__ low,
                                              const float* __restrict__ Xs,
                                              const float* __restrict__ Xq,
                                              const float* __restrict__ m,
                                              const float* __restrict__ kp,
                                              const float* __restrict__ nup,
                                              float* __restrict__ L, float* __restrict__ W,
                                              u16* __restrict__ ABh, u16* __restrict__ ABl,
                                              u16* __restrict__ Wh, u16* __restrict__ Wl,
                                              float* __restrict__ S) {
  int bid = blockIdx.x, tid = threadIdx.x;
  if (bid < 1024) {
    int t = bid * 256 + tid;
    int i = t >> 9, j = t & 511;
    float v = (i == j) ? fabsf(diag[i]) : (i > j ? low[t] : 0.f);
    L[t] = v;
    if (i < j) { W[t] = 0.f; Wh[t] = 0; Wl[t] = 0; }
  } else if (bid < 1088) {
    int c = bid - 1024;
    float kappa = kp[0];
    float kn = fabsf(kappa) + 1e-6f + 5.0f;
    float xw = 5.0f / kn;
    float mw = fabsf(kappa + 1e-6f) / kn;
    float sw = sqrtf((fabsf(kappa) + 1e-6f) / kn);
    const float is5 = 0.44721359549995793f;
    for (int d = tid; d < D; d += 256) {
      float x[5];
#pragma unroll
      for (int s = 0; s < 5; ++s) x[s] = Xs[(size_t)(c * 5 + s) * D + d];
      float xm = (x[0] + x[1] + x[2] + x[3] + x[4]) * 0.2f;
      float mv = m[d];
      float rowv[8];
#pragma unroll
      for (int s = 0; s < 5; ++s) rowv[s] = x[s] * is5;
      rowv[5] = sw * (xm - mv);
      rowv[6] = mw * mv + xw * xm;
      rowv[7] = 0.f;
#pragma unroll
      for (int s = 0; s < 8; ++s) {
        size_t gi = (size_t)(c * 8 + s) * D + d;
        u16 hh, ll; split2(rowv[s], hh, ll);
        ABh[gi] = hh; ABl[gi] = ll;
      }
    }
  } else if (bid == 1088) {
    if (tid >= 64) return;
    float part = 0.f;
    for (int i = tid; i < D; i += 64) part += logf(fabsf(diag[i]));
    part = wred(part);
    if (tid != 0) return;
    float lda = 2.f * part;
    float kappa = kp[0], nu = nup[0];
    float kn = fabsf(kappa) + 1e-6f + 5.0f;
    float sp = fmaxf(nu, (float)(D - 1) + 1e-6f) + 5.0f - (float)D + 2.0f;
    float bias_shared = lgammaf(0.5f * (sp + (float)D)) - lgammaf(0.5f * sp)
                      - 0.5f * (float)D * logf(sp);
    float scale = kn * sp / (kn + 1.0f);
    S[3] = bias_shared;
    S[8] = 1.f / scale;
    S[9] = (float)D * logf(scale) + lda;
    S[10] = 0.5f * (sp + (float)D);
    S[11] = 1.f / sp;
  } else {
    int idx = bid - 1089;                 // 0..511, 4 Xq rows each
    size_t base = (size_t)512 * D + (size_t)idx * 2048;
    for (int i = tid; i < 2048; i += 256) {
      float v = Xq[(size_t)idx * 2048 + i];
      u16 hh, ll; split2(v, hh, ll);
      ABh[base + i] = hh; ABl[base + i] = ll;
    }
  }
}

#define MPAD 130

template <int N>
__device__ inline void lds_mm(float (*M)[MPAD], int ar, int ac, int br, int bc,
                              int cr, int cc, bool neg) {
  const int T = N / 16;
  int tx = (threadIdx.x & 15) * T, ty = (threadIdx.x >> 4) * T;
  float acc[T][T];
#pragma unroll
  for (int i = 0; i < T; ++i)
#pragma unroll
    for (int j = 0; j < T; ++j) acc[i][j] = 0.f;
#pragma unroll 8
  for (int k = 0; k < N; ++k) {
    float a[T], b[T];
#pragma unroll
    for (int i = 0; i < T; ++i) a[i] = M[ar + ty + i][ac + k];
#pragma unroll
    for (int j = 0; j < T; ++j) b[j] = M[br + k][bc + tx + j];
#pragma unroll
    for (int i = 0; i < T; ++i)
#pragma unroll
      for (int j = 0; j < T; ++j) acc[i][j] += a[i] * b[j];
  }
#pragma unroll
  for (int i = 0; i < T; ++i)
#pragma unroll
    for (int j = 0; j < T; ++j)
      M[cr + ty + i][cc + tx + j] = neg ? -acc[i][j] : acc[i][j];
}

// Invert a 128x128 diagonal block of L entirely in LDS; write W fp32 + bf16 h/l.
__global__ __launch_bounds__(256) void k_inv128(const float* __restrict__ L,
                                                float* __restrict__ W,
                                                u16* __restrict__ Wh,
                                                u16* __restrict__ Wl) {
  __shared__ float M[128][MPAD];
  int p = blockIdx.x * 128;
  int tid = threadIdx.x;
  for (int idx = tid; idx < 128 * 32; idx += 256) {
    int r = idx >> 5, c4 = (idx & 31) << 2;
    *reinterpret_cast<float4*>(&M[r][c4]) =
        *reinterpret_cast<const float4*>(&L[(size_t)(p + r) * D + p + c4]);
  }
  __syncthreads();
  {
    float x[16];
    int q = tid >> 4, col = tid & 15;
    if (tid < 128) {
      int b = q << 4;
#pragma unroll
      for (int i = 0; i < 16; ++i) {
        float acc = 0.f;
#pragma unroll
        for (int k = 0; k < i; ++k) acc += M[b + i][b + k] * x[k];
        x[i] = (((i == col) ? 1.f : 0.f) - acc) / M[b + i][b + i];
      }
    }
    __syncthreads();
    if (tid < 128) {
      int b = q << 4;
#pragma unroll
      for (int i = 0; i < 16; ++i) M[b + i][b + col] = x[i];
    }
    __syncthreads();
  }
#define LEVEL(n)                                                         \
  for (int pp = 0; pp < 128 / (2 * n); ++pp) {                           \
    int r0 = 2 * n * pp;                                                 \
    lds_mm<n>(M, r0 + n, r0, r0, r0, r0, r0 + n, false);                 \
  }                                                                      \
  __syncthreads();                                                       \
  for (int pp = 0; pp < 128 / (2 * n); ++pp) {                           \
    int r0 = 2 * n * pp;                                                 \
    lds_mm<n>(M, r0 + n, r0 + n, r0, r0 + n, r0 + n, r0, true);          \
  }                                                                      \
  __syncthreads();
  LEVEL(16)
  LEVEL(32)
  LEVEL(64)
#undef LEVEL
  for (int idx = tid; idx < 128 * 32; idx += 256) {
    int r = idx >> 5, c4 = (idx & 31) << 2;
    float4 v = *reinterpret_cast<const float4*>(&M[r][c4]);
    if (c4 + 0 > r) v.x = 0.f;
    if (c4 + 1 > r) v.y = 0.f;
    if (c4 + 2 > r) v.z = 0.f;
    if (c4 + 3 > r) v.w = 0.f;
    size_t gi = (size_t)(p + r) * D + p + c4;
    *reinterpret_cast<float4*>(&W[gi]) = v;
    float vv[4] = {v.x, v.y, v.z, v.w};
#pragma unroll
    for (int e = 0; e < 4; ++e) {
      u16 hh, ll; split2(vv[e], hh, ll);
      Wh[gi + e] = hh; Wl[gi + e] = ll;
    }
  }
}

// Batched NN matmul on submatrices: C = alpha*A@B (n x n), optional bf16 h/l out.
__global__ __launch_bounds__(256) void k_nn(const float* __restrict__ A, int lda, int aOff0, int aZ,
                                            const float* __restrict__ B, int ldb, int bOff0, int bZ,
                                            float* __restrict__ C, int ldc, int cOff0, int cZ,
                                            int n, float alpha,
                                            u16* __restrict__ wh, u16* __restrict__ wl) {
  __shared__ float As[32][33];
  __shared__ float Bs[32][33];
  int z = blockIdx.z;
  const float* Ab = A + aOff0 + (size_t)z * aZ;
  const float* Bb = B + bOff0 + (size_t)z * bZ;
  size_t cbase = (size_t)cOff0 + (size_t)z * cZ;
  int bm = blockIdx.y * 32, bn = blockIdx.x * 32;
  int tid = threadIdx.x;
  int tx = tid & 15, ty = tid >> 4;
  float acc[2][2] = {};
  for (int k0 = 0; k0 < n; k0 += 32) {
    __syncthreads();
    for (int idx = tid; idx < 1024; idx += 256) {
      int r = idx >> 5, c = idx & 31;
      As[r][c] = Ab[(size_t)(bm + r) * lda + k0 + c];
      Bs[r][c] = Bb[(size_t)(k0 + r) * ldb + bn + c];
    }
    __syncthreads();
#pragma unroll
    for (int kk = 0; kk < 32; ++kk) {
      float a0 = As[ty * 2 + 0][kk], a1 = As[ty * 2 + 1][kk];
      float b0 = Bs[kk][tx * 2 + 0], b1 = Bs[kk][tx * 2 + 1];
      acc[0][0] += a0 * b0; acc[0][1] += a0 * b1;
      acc[1][0] += a1 * b0; acc[1][1] += a1 * b1;
    }
  }
#pragma unroll
  for (int i = 0; i < 2; ++i)
#pragma unroll
    for (int j = 0; j < 2; ++j) {
      size_t gi = cbase + (size_t)(bm + ty * 2 + i) * ldc + bn + tx * 2 + j;
      float v = alpha * acc[i][j];
      C[gi] = v;
      if (wh) { u16 hh, ll; split2(v, hh, ll); wh[gi] = hh; wl[gi] = ll; }
    }
}

// GEMM1 (MFMA split-bf16): YY = [Ubp;Xq] @ W^T, tri-clipped. Fused: fp32 YYf
// write (rows<512), bf16 h/l YY write (all rows), aq += rowsumsq (rows>=512).
__global__ __launch_bounds__(256) void k_mf1(const u16* __restrict__ ABh, const u16* __restrict__ ABl,
                                             const u16* __restrict__ Wh, const u16* __restrict__ Wl,
                                             u16* __restrict__ YYh, u16* __restrict__ YYl,
                                             float* __restrict__ YYf, float* __restrict__ aq) {
  int tid = threadIdx.x, w = tid >> 6, lane = tid & 63;
  int m0 = blockIdx.x * 64 + w * 16;
  int bn = blockIdx.y * 64;
  int lr = lane & 15, kof = (lane >> 4) * 8;
  const u16* ah_p = ABh + (size_t)(m0 + lr) * D + kof;
  const u16* al_p = ABl + (size_t)(m0 + lr) * D + kof;
  const u16* bh_p = Wh + (size_t)(bn + lr) * D + kof;
  const u16* bl_p = Wl + (size_t)(bn + lr) * D + kof;
  f4 acc[4];
#pragma unroll
  for (int nf = 0; nf < 4; ++nf) acc[nf] = (f4){0.f, 0.f, 0.f, 0.f};
  int Klim = bn + 64;
#pragma unroll 2
  for (int k0 = 0; k0 < Klim; k0 += 32) {
    bf8 ah = *reinterpret_cast<const bf8*>(ah_p + k0);
    bf8 al = *reinterpret_cast<const bf8*>(al_p + k0);
    bf8 bh[4], bl[4];
#pragma unroll
    for (int nf = 0; nf < 4; ++nf) {
      bh[nf] = *reinterpret_cast<const bf8*>(bh_p + (size_t)nf * 16 * D + k0);
      bl[nf] = *reinterpret_cast<const bf8*>(bl_p + (size_t)nf * 16 * D + k0);
    }
#pragma unroll
    for (int nf = 0; nf < 4; ++nf)
      acc[nf] = __builtin_amdgcn_mfma_f32_16x16x32_bf16(ah, bh[nf], acc[nf], 0, 0, 0);
#pragma unroll
    for (int nf = 0; nf < 4; ++nf)
      acc[nf] = __builtin_amdgcn_mfma_f32_16x16x32_bf16(ah, bl[nf], acc[nf], 0, 0, 0);
#pragma unroll
    for (int nf = 0; nf < 4; ++nf)
      acc[nf] = __builtin_amdgcn_mfma_f32_16x16x32_bf16(al, bh[nf], acc[nf], 0, 0, 0);
  }
  int rbase = m0 + ((lane >> 4) << 2);   // C layout: row=(lane>>4)*4+reg, col=lane&15
#pragma unroll
  for (int reg = 0; reg < 4; ++reg) {
    int row = rbase + reg;
    float sq = 0.f;
#pragma unroll
    for (int nf = 0; nf < 4; ++nf) {
      float v = acc[nf][reg];
      size_t gi = (size_t)row * D + bn + nf * 16 + lr;
      u16 hh, ll; split2(v, hh, ll);
      YYh[gi] = hh; YYl[gi] = ll;
      if (row < 512) YYf[gi] = v;
      sq += v * v;
    }
    if (row >= 512) {                    // uniform per wave (m0 mult of 16)
#pragma unroll
      for (int mk = 1; mk < 16; mk <<= 1) sq += __shfl_xor(sq, mk);
      if (lr == 0) atomicAdd(&aq[row - 512], sq);
    }
  }
}

// GEMM2 (MFMA split-bf16) + fused MetaQDA epilogue: out = epi(Y @ UWp^T).
__global__ __launch_bounds__(256) void k_mf2(const u16* __restrict__ Yh, const u16* __restrict__ Yl,
                                             const u16* __restrict__ Bh, const u16* __restrict__ Bl,
                                             const float* __restrict__ aq, const float* __restrict__ sv,
                                             const float* __restrict__ Minv, const float* __restrict__ biasv,
                                             const float* __restrict__ hb, const float* __restrict__ S,
                                             float* __restrict__ out) {
  __shared__ float Csh[4][16][68];
  int tid = threadIdx.x, w = tid >> 6, lane = tid & 63;
  int bm = blockIdx.x * 64, m0 = bm + w * 16;
  int bn = blockIdx.y * 64;
  int lr = lane & 15, kof = (lane >> 4) * 8;
  const u16* ah_p = Yh + (size_t)(m0 + lr) * D + kof;
  const u16* al_p = Yl + (size_t)(m0 + lr) * D + kof;
  const u16* bh_p = Bh + (size_t)(bn + lr) * D + kof;
  const u16* bl_p = Bl + (size_t)(bn + lr) * D + kof;
  f4 acc[4];
#pragma unroll
  for (int nf = 0; nf < 4; ++nf) acc[nf] = (f4){0.f, 0.f, 0.f, 0.f};
#pragma unroll 2
  for (int k0 = 0; k0 < D; k0 += 32) {
    bf8 ah = *reinterpret_cast<const bf8*>(ah_p + k0);
    bf8 al = *reinterpret_cast<const bf8*>(al_p + k0);
    bf8 bh[4], bl[4];
#pragma unroll
    for (int nf = 0; nf < 4; ++nf) {
      bh[nf] = *reinterpret_cast<const bf8*>(bh_p + (size_t)nf * 16 * D + k0);
      bl[nf] = *reinterpret_cast<const bf8*>(bl_p + (size_t)nf * 16 * D + k0);
    }
#pragma unroll
    for (int nf = 0; nf < 4; ++nf)
      acc[nf] = __builtin_amdgcn_mfma_f32_16x16x32_bf16(ah, bh[nf], acc[nf], 0, 0, 0);
#pragma unroll
    for (int nf = 0; nf < 4; ++nf)
      acc[nf] = __builtin_amdgcn_mfma_f32_16x16x32_bf16(ah, bl[nf], acc[nf], 0, 0, 0);
#pragma unroll
    for (int nf = 0; nf < 4; ++nf)
      acc[nf] = __builtin_amdgcn_mfma_f32_16x16x32_bf16(al, bh[nf], acc[nf], 0, 0, 0);
  }
#pragma unroll
  for (int reg = 0; reg < 4; ++reg)
#pragma unroll
    for (int nf = 0; nf < 4; ++nf)
      Csh[w][((lane >> 4) << 2) + reg][nf * 16 + lr] = acc[nf][reg];
  __syncthreads();
  float s8 = S[8], s10 = S[10], s11 = S[11];
  int r = lr;
  int q = m0 + r;
  float aqv = aq[q];
#pragma unroll
  for (int cc = 0; cc < 2; ++cc) {
    int cl = ((lane >> 4) << 1) + cc;    // class within tile 0..7
    int c = blockIdx.y * 8 + cl;
    const float* t = &Csh[w][r][cl * 8];
    float e[6];
#pragma unroll
    for (int j = 0; j < 6; ++j) e[j] = t[j] - sv[c * 6 + j];
    float quad = 0.f;
#pragma unroll
    for (int i = 0; i < 6; ++i) {
      float a = 0.f;
#pragma unroll
      for (int j = 0; j < 6; ++j) a += Minv[c * 36 + i * 6 + j] * e[j];
      quad += e[i] * a;
    }
    float dist = (aqv - 2.f * t[6] + hb[c] - quad) * s8;
    out[(size_t)q * NC + c] = biasv[c] - s10 * log1pf(dist * s11);
  }
}

// per class: 7x7 Gram of fp32 UWp rows -> Minv, logdet, bias, sv, h.
__global__ __launch_bounds__(256) void k_msmall(const float* __restrict__ YYf,
                                                const float* __restrict__ S,
                                                float* __restrict__ Minv, float* __restrict__ biasv,
                                                float* __restrict__ hbuf, float* __restrict__ svec) {
  __shared__ float4 R4[7 * 128];
  __shared__ float Dsh[49];
  int c = blockIdx.x, tid = threadIdx.x;
  int lane = tid & 63, wave = tid >> 6;
  const float4* src = reinterpret_cast<const float4*>(YYf + (size_t)c * 8 * D);
  for (int idx = tid; idx < 7 * 128; idx += 256) R4[idx] = src[idx];
  __syncthreads();
  const float* R = reinterpret_cast<const float*>(R4);
  const int PI[28] = {0,0,0,0,0,0,0, 1,1,1,1,1,1, 2,2,2,2,2, 3,3,3,3, 4,4,4, 5,5, 6};
  const int PJ[28] = {0,1,2,3,4,5,6, 1,2,3,4,5,6, 2,3,4,5,6, 3,4,5,6, 4,5,6, 5,6, 6};
  for (int p = wave; p < 28; p += 4) {
    int i = PI[p], j = PJ[p];
    float part = 0.f;
#pragma unroll
    for (int it = 0; it < 8; ++it) {
      int d = lane + it * 64;
      part += R[i * D + d] * R[j * D + d];
    }
    part = wred(part);
    if (lane == 0) { Dsh[i * 7 + j] = part; Dsh[j * 7 + i] = part; }
  }
  __syncthreads();
  if (tid == 0) {
    float Mm[6][6], Rc[6][6], Rin[6][6];
    for (int i = 0; i < 6; ++i)
      for (int j = 0; j < 6; ++j) {
        Mm[i][j] = Dsh[i * 7 + j] + (i == j ? 1.f : 0.f);
        Rc[i][j] = 0.f; Rin[i][j] = 0.f;
      }
    float logdetM = 0.f;
    for (int i = 0; i < 6; ++i) {
      float s = Mm[i][i];
      for (int k = 0; k < i; ++k) s -= Rc[i][k] * Rc[i][k];
      float rii = sqrtf(s);
      Rc[i][i] = rii;
      logdetM += logf(rii);
      for (int r = i + 1; r < 6; ++r) {
        float s2 = Mm[r][i];
        for (int k = 0; k < i; ++k) s2 -= Rc[r][k] * Rc[i][k];
        Rc[r][i] = s2 / rii;
      }
    }
    logdetM *= 2.f;
    for (int j = 0; j < 6; ++j) {
      Rin[j][j] = 1.f / Rc[j][j];
      for (int i = j + 1; i < 6; ++i) {
        float s3 = 0.f;
        for (int k = j; k < i; ++k) s3 += Rc[i][k] * Rin[k][j];
        Rin[i][j] = -s3 / Rc[i][i];
      }
    }
    for (int i = 0; i < 6; ++i)
      for (int j = 0; j < 6; ++j) {
        float s4 = 0.f;
        for (int k = 0; k < 6; ++k) s4 += Rin[k][i] * Rin[k][j];
        Minv[c * 36 + i * 6 + j] = s4;
      }
    for (int j = 0; j < 6; ++j) svec[c * 6 + j] = Dsh[j * 7 + 6];
    hbuf[c] = Dsh[48];
    biasv[c] = S[3] - 0.5f * (S[9] + logdetM);
  }
}

extern "C" void kernel_launch(void* const* d_in, const int* in_sizes, int n_in,
                              void* d_out, int out_size, void* d_ws, size_t ws_size,
                              hipStream_t stream) {
  const float* Xs   = (const float*)d_in[0];
  const float* Xq   = (const float*)d_in[2];
  const float* m    = (const float*)d_in[3];
  const float* kap  = (const float*)d_in[4];
  const float* nu   = (const float*)d_in[5];
  const float* diag = (const float*)d_in[6];
  const float* low  = (const float*)d_in[7];
  float* ws = (float*)d_ws;

  float* S    = ws + OFF_S;
  float* L    = ws + OFF_L;
  float* YYf  = ws + OFF_L;      // aliases L: all L reads finish before k_mf1
  float* W    = ws + OFF_W;
  float* TMP  = ws + OFF_TMP;
  u16*   ABh  = (u16*)(ws + OFF_ABH);
  u16*   ABl  = (u16*)(ws + OFF_ABL);
  u16*   Wh   = (u16*)(ws + OFF_WH);
  u16*   Wl   = (u16*)(ws + OFF_WL);
  u16*   YYh  = (u16*)(ws + OFF_YYH);
  u16*   YYl  = (u16*)(ws + OFF_YYL);
  float* aq   = ws + OFF_AQ;
  float* Minv = ws + OFF_MINV;
  float* bias = ws + OFF_BIAS;
  float* hb   = ws + OFF_H;
  float* sv   = ws + OFF_SV;

  hipLaunchKernelGGL(k_prep, dim3(1601), dim3(256), 0, stream,
                     diag, low, Xs, Xq, m, kap, nu, L, W, ABh, ABl, Wh, Wl, S);
  hipLaunchKernelGGL(k_inv128, dim3(4), dim3(256), 0, stream, L, W, Wh, Wl);
  // doubling level n=128 (2 pairs) — restores the off-diag blocks R5/R6 missed
  hipLaunchKernelGGL(k_nn, dim3(4, 4, 2), dim3(256), 0, stream,
                     L, D, 128 * D, 256 * (D + 1),
                     W, D, 0, 256 * (D + 1),
                     TMP, 128, 0, 128 * 128, 128, 1.0f, (u16*)nullptr, (u16*)nullptr);
  hipLaunchKernelGGL(k_nn, dim3(4, 4, 2), dim3(256), 0, stream,
                     W, D, 128 * (D + 1), 256 * (D + 1),
                     TMP, 128, 0, 128 * 128,
                     W, D, 128 * D, 256 * (D + 1), 128, -1.0f, Wh, Wl);
  // doubling level n=256 (1 pair)
  hipLaunchKernelGGL(k_nn, dim3(8, 8, 1), dim3(256), 0, stream,
                     L, D, 256 * D, 0,
                     W, D, 0, 0,
                     TMP, 256, 0, 0, 256, 1.0f, (u16*)nullptr, (u16*)nullptr);
  hipLaunchKernelGGL(k_nn, dim3(8, 8, 1), dim3(256), 0, stream,
                     W, D, 256 * (D + 1), 0,
                     TMP, 256, 0, 0,
                     W, D, 256 * D, 0, 256, -1.0f, Wh, Wl);
  hipMemsetAsync(aq, 0, NQ * sizeof(float), stream);
  // GEMM1: YY = [Ubp;Xq] @ W^T (2560x512x512 tri-clipped) + aq atomics
  hipLaunchKernelGGL(k_mf1, dim3(40, 8), dim3(256), 0, stream,
                     ABh, ABl, Wh, Wl, YYh, YYl, YYf, aq);
  hipLaunchKernelGGL(k_msmall, dim3(NC), dim3(256), 0, stream, YYf, S, Minv, bias, hb, sv);
  // GEMM2: out = epilogue(Y @ UWp^T) (2048x512x512)
  hipLaunchKernelGGL(k_mf2, dim3(32, 8), dim3(256), 0, stream,
                     YYh + (size_t)512 * D, YYl + (size_t)512 * D, YYh, YYl,
                     aq, sv, Minv, bias, hb, S, (float*)d_out);
}